// Round 1
// 448.063 us; speedup vs baseline: 1.2697x; 1.2697x over previous
//
#include <hip/hip_runtime.h>
#include <hip/hip_bf16.h>

#define NN 50000
#define EE 1600000
#define FIN 128
#define HH 32
#define CC 16

typedef unsigned short u16;
typedef unsigned int u32;

__device__ __forceinline__ float bf2f(u16 u) {
    union { u32 i; float f; } v; v.i = ((u32)u) << 16; return v.f;
}
__device__ __forceinline__ u16 f2bf(float f) {
    union { float f; u32 i; } v; v.f = f;
    u32 x = v.i;
    return (u16)((x + 0x7fffu + ((x >> 16) & 1u)) >> 16);  // RNE
}

// ---- dtype probe: flag=1 if float tensors are bf16, 0 if fp32 ----
__global__ __launch_bounds__(256) void k_probe(const u32* __restrict__ xw_words, int* __restrict__ flag) {
    __shared__ int cs;
    if (threadIdx.x == 0) cs = 0;
    __syncthreads();
    int c = 0;
    for (int i = threadIdx.x; i < 512; i += 256) {
        float v = fabsf(bf2f((u16)(xw_words[i] & 0xffffu)));
        if (v >= 6.0e-8f && v <= 64.0f) c++;
    }
    atomicAdd(&cs, c);
    __syncthreads();
    if (threadIdx.x == 0) *flag = (cs > 384) ? 1 : 0;
}

__global__ __launch_bounds__(256) void k_zero(int* __restrict__ p, int n) {
    int i = blockIdx.x * 256 + threadIdx.x;
    if (i < n) p[i] = 0;
}

__global__ __launch_bounds__(256) void k_deg(const int* __restrict__ dst, int* __restrict__ cnt) {
    int e = blockIdx.x * 256 + threadIdx.x;
    if (e < EE) atomicAdd(&cnt[dst[e]], 1);
}

__global__ __launch_bounds__(256) void k_dis(const int* __restrict__ cnt, float* __restrict__ dis) {
    int i = blockIdx.x * 256 + threadIdx.x;
    if (i < NN) dis[i] = rsqrtf((float)cnt[i] + 1.0f);  // +1 = self-loop
}

// ---- exclusive prefix sum of cnt -> rowptr[0..NN], single block ----
__global__ __launch_bounds__(1024) void k_scan(const int* __restrict__ cnt, int* __restrict__ rowptr) {
    __shared__ int ps[1024];
    const int t = threadIdx.x;
    const int CH = (NN + 1023) / 1024;  // 49
    int b = t * CH;
    int e = b + CH; if (e > NN) e = NN;
    int s = 0;
    for (int i = b; i < e; ++i) s += cnt[i];
    ps[t] = s;
    __syncthreads();
    for (int off = 1; off < 1024; off <<= 1) {
        int v = (t >= off) ? ps[t - off] : 0;
        __syncthreads();
        ps[t] += v;
        __syncthreads();
    }
    int run = (t == 0) ? 0 : ps[t - 1];
    for (int i = b; i < e; ++i) { rowptr[i] = run; run += cnt[i]; }
    if (t == 1023) rowptr[NN] = ps[1023];
}

__global__ __launch_bounds__(256) void k_fill(const int* __restrict__ rowptr, int* __restrict__ fill) {
    int i = blockIdx.x * 256 + threadIdx.x;
    if (i < NN) fill[i] = rowptr[i];
}

// ---- bucket edges by dst; src fits in u16 (NN < 65536) ----
__global__ __launch_bounds__(256) void k_bucket(const int* __restrict__ src, const int* __restrict__ dst,
                                                int* __restrict__ fill, u16* __restrict__ entries) {
    int e = blockIdx.x * 256 + threadIdx.x;
    if (e < EE) {
        int d = dst[e];
        int pos = atomicAdd(&fill[d], 1);
        entries[pos] = (u16)src[e];
    }
}

// ---- xw = x @ W1 -> bf16 [NN,32]; x is [NN,128] bf16 or fp32 per flag ----
__global__ __launch_bounds__(256) void k_xw1(const void* __restrict__ xv, const void* __restrict__ W1v,
                                             const int* __restrict__ flag, u16* __restrict__ xwb) {
    __shared__ float wsm[FIN * HH];   // 16 KB
    __shared__ float xs[128][33];     // 16.9 KB
    const int f = *flag;
    const int tid = threadIdx.x;
    if (f) {
        const u16* W1 = (const u16*)W1v;
        for (int i = tid; i < FIN * HH; i += 256) wsm[i] = bf2f(W1[i]);
    } else {
        const float* W1 = (const float*)W1v;
        for (int i = tid; i < FIN * HH; i += 256) wsm[i] = W1[i];
    }
    const int n0 = blockIdx.x * 128;
    const int ct = tid & 7, rg = tid >> 3;
    const int lr = tid >> 1, lh = tid & 1;
    int ln = n0 + lr; if (ln >= NN) ln = NN - 1;
    float acc[4][4] = {};
    for (int kc = 0; kc < FIN; kc += 32) {
        __syncthreads();
        float* dq = &xs[lr][lh * 16];
        if (f) {
            const u16* lp = (const u16*)xv + (size_t)ln * FIN + lh * 16 + kc;
            uint4 a = *(const uint4*)lp;
            uint4 b = *(const uint4*)(lp + 8);
            u32 aw[4] = {a.x, a.y, a.z, a.w}, bw[4] = {b.x, b.y, b.z, b.w};
            #pragma unroll
            for (int i = 0; i < 4; ++i) {
                dq[2*i]     = bf2f((u16)(aw[i] & 0xffffu));
                dq[2*i+1]   = bf2f((u16)(aw[i] >> 16));
                dq[8+2*i]   = bf2f((u16)(bw[i] & 0xffffu));
                dq[8+2*i+1] = bf2f((u16)(bw[i] >> 16));
            }
        } else {
            const float* lp = (const float*)xv + (size_t)ln * FIN + lh * 16 + kc;
            #pragma unroll
            for (int i = 0; i < 4; ++i) {
                float4 t = *(const float4*)(lp + 4 * i);
                dq[4*i] = t.x; dq[4*i+1] = t.y; dq[4*i+2] = t.z; dq[4*i+3] = t.w;
            }
        }
        __syncthreads();
        #pragma unroll
        for (int k = 0; k < 32; ++k) {
            float4 wv = *(const float4*)&wsm[(kc + k) * HH + ct * 4];
            #pragma unroll
            for (int j = 0; j < 4; ++j) {
                float xvv = xs[rg * 4 + j][k];
                acc[j][0] = fmaf(xvv, wv.x, acc[j][0]);
                acc[j][1] = fmaf(xvv, wv.y, acc[j][1]);
                acc[j][2] = fmaf(xvv, wv.z, acc[j][2]);
                acc[j][3] = fmaf(xvv, wv.w, acc[j][3]);
            }
        }
    }
    #pragma unroll
    for (int j = 0; j < 4; ++j) {
        int n = n0 + rg * 4 + j;
        if (n < NN) {
            ushort4 o;
            o.x = f2bf(acc[j][0]); o.y = f2bf(acc[j][1]);
            o.z = f2bf(acc[j][2]); o.w = f2bf(acc[j][3]);
            *(ushort4*)&xwb[(size_t)n * HH + ct * 4] = o;
        }
    }
}

// ---- xw = h1 @ W2 -> bf16; h1 is bf16 [NN,32] (internal) ----
__global__ __launch_bounds__(256) void k_xw2(const u16* __restrict__ h1, const void* __restrict__ W2v,
                                             const int* __restrict__ flag, u16* __restrict__ xwb) {
    __shared__ float wsm[HH * HH];
    __shared__ float xs[128][33];
    const int f = *flag;
    const int tid = threadIdx.x;
    if (f) {
        const u16* W2 = (const u16*)W2v;
        for (int i = tid; i < HH * HH; i += 256) wsm[i] = bf2f(W2[i]);
    } else {
        const float* W2 = (const float*)W2v;
        for (int i = tid; i < HH * HH; i += 256) wsm[i] = W2[i];
    }
    const int n0 = blockIdx.x * 128;
    const int lr = tid >> 1, lh = tid & 1;
    int ln = n0 + lr; if (ln >= NN) ln = NN - 1;
    const u16* lp = h1 + (size_t)ln * HH + lh * 16;
    uint4 a = *(const uint4*)lp;
    uint4 b = *(const uint4*)(lp + 8);
    float* dq = &xs[lr][lh * 16];
    u32 aw[4] = {a.x, a.y, a.z, a.w}, bw[4] = {b.x, b.y, b.z, b.w};
    #pragma unroll
    for (int i = 0; i < 4; ++i) {
        dq[2*i]     = bf2f((u16)(aw[i] & 0xffffu));
        dq[2*i+1]   = bf2f((u16)(aw[i] >> 16));
        dq[8+2*i]   = bf2f((u16)(bw[i] & 0xffffu));
        dq[8+2*i+1] = bf2f((u16)(bw[i] >> 16));
    }
    __syncthreads();
    const int ct = tid & 7, rg = tid >> 3;
    float acc[4][4] = {};
    #pragma unroll
    for (int k = 0; k < 32; ++k) {
        float4 wv = *(const float4*)&wsm[k * HH + ct * 4];
        #pragma unroll
        for (int j = 0; j < 4; ++j) {
            float xv = xs[rg * 4 + j][k];
            acc[j][0] = fmaf(xv, wv.x, acc[j][0]);
            acc[j][1] = fmaf(xv, wv.y, acc[j][1]);
            acc[j][2] = fmaf(xv, wv.z, acc[j][2]);
            acc[j][3] = fmaf(xv, wv.w, acc[j][3]);
        }
    }
    #pragma unroll
    for (int j = 0; j < 4; ++j) {
        int n = n0 + rg * 4 + j;
        if (n < NN) {
            ushort4 o;
            o.x = f2bf(acc[j][0]); o.y = f2bf(acc[j][1]);
            o.z = f2bf(acc[j][2]); o.w = f2bf(acc[j][3]);
            *(ushort4*)&xwb[(size_t)n * HH + ct * 4] = o;
        }
    }
}

// ---- CSR gather + fused epilogue: one node per 32-lane group ----
// out[n] = tanh( dis[n] * ( dis[n]*xw[n] + sum_{s in N(n)} dis[s]*xw[s] ) + bias )
__global__ __launch_bounds__(256) void k_gather(const int* __restrict__ rowptr, const u16* __restrict__ entries,
                                                const u16* __restrict__ xwb, const float* __restrict__ dis,
                                                const void* __restrict__ bv, const int* __restrict__ flag,
                                                int force16, u16* __restrict__ dst16, float* __restrict__ dst32) {
    const int f = *flag;
    int g = (blockIdx.x * 256 + threadIdx.x) >> 5;  // node
    int lane = threadIdx.x & 31;                    // channel
    if (g >= NN) return;
    float bias = f ? bf2f(((const u16*)bv)[lane]) : ((const float*)bv)[lane];
    const int beg = rowptr[g], end = rowptr[g + 1];
    const float dd = dis[g];
    float acc0 = dd * bf2f(xwb[(size_t)g * HH + lane]);  // self-loop term
    float acc1 = 0.f, acc2 = 0.f, acc3 = 0.f;
    int i = beg;
    for (; i + 4 <= end; i += 4) {
        int s0 = entries[i], s1 = entries[i + 1], s2 = entries[i + 2], s3 = entries[i + 3];
        float w0 = dis[s0], w1 = dis[s1], w2 = dis[s2], w3 = dis[s3];
        acc0 = fmaf(w0, bf2f(xwb[(size_t)s0 * HH + lane]), acc0);
        acc1 = fmaf(w1, bf2f(xwb[(size_t)s1 * HH + lane]), acc1);
        acc2 = fmaf(w2, bf2f(xwb[(size_t)s2 * HH + lane]), acc2);
        acc3 = fmaf(w3, bf2f(xwb[(size_t)s3 * HH + lane]), acc3);
    }
    for (; i < end; ++i) {
        int s = entries[i];
        acc0 = fmaf(dis[s], bf2f(xwb[(size_t)s * HH + lane]), acc0);
    }
    float v = tanhf(fmaf(dd, (acc0 + acc1) + (acc2 + acc3), bias));
    size_t idx = (size_t)g * HH + lane;
    if (force16 | f) dst16[idx] = f2bf(v);
    else             dst32[idx] = v;
}

// ---- classifier: logits = h2 @ Wc + bc ----
__global__ __launch_bounds__(256) void k_cls(void* __restrict__ outbase, const void* __restrict__ Wcv,
                                             const void* __restrict__ bcv, const int* __restrict__ flag) {
    __shared__ float wsm[HH * CC];
    __shared__ float bs[CC];
    const int f = *flag;
    int tid = threadIdx.x;
    if (f) {
        const u16* Wc = (const u16*)Wcv;
        for (int i = tid; i < HH * CC; i += 256) wsm[i] = bf2f(Wc[i]);
        if (tid < CC) bs[tid] = bf2f(((const u16*)bcv)[tid]);
    } else {
        const float* Wc = (const float*)Wcv;
        for (int i = tid; i < HH * CC; i += 256) wsm[i] = Wc[i];
        if (tid < CC) bs[tid] = ((const float*)bcv)[tid];
    }
    __syncthreads();
    int t = blockIdx.x * 256 + tid;
    int n = t >> 4;
    if (n < NN) {
        int cl = t & 15;
        float acc = bs[cl];
        if (f) {
            const u16* r = (const u16*)outbase + (size_t)NN * CC + (size_t)n * HH;
            #pragma unroll
            for (int k = 0; k < HH; ++k) acc = fmaf(bf2f(r[k]), wsm[k * CC + cl], acc);
            ((u16*)outbase)[t] = f2bf(acc);
        } else {
            const float* r = (const float*)outbase + (size_t)NN * CC + (size_t)n * HH;
            #pragma unroll
            for (int k = 0; k < HH; ++k) acc = fmaf(r[k], wsm[k * CC + cl], acc);
            ((float*)outbase)[t] = acc;
        }
    }
}

extern "C" void kernel_launch(void* const* d_in, const int* in_sizes, int n_in,
                              void* d_out, int out_size, void* d_ws, size_t ws_size,
                              hipStream_t stream) {
    const void* x  = d_in[0];
    const int*  ei = (const int*)d_in[1];
    const void* W1 = d_in[2];
    const void* b1 = d_in[3];
    const void* W2 = d_in[4];
    const void* b2 = d_in[5];
    const void* Wc = d_in[6];
    const void* bc = d_in[7];
    const int* srcv = ei;
    const int* dstv = ei + EE;

    // ws layout (bytes), total ~7.21 MB (prev session proved ws >= 9.8 MB):
    //   [0,4)           flag
    //   [4096, 204096)  dis   f32[N]
    //   [204800,404804) rowptr int[N+1]
    //   [405504,605504) cnt   int[N]
    //   [606208,806208) fill  int[N]
    //   [806912, 4006912)  xwb     bf16[N*32]
    //   [4007936, 7207936) entries u16[E]
    char*  ws      = (char*)d_ws;
    int*   flag    = (int*)ws;
    float* dis     = (float*)(ws + 4096);
    int*   rowptr  = (int*)(ws + 204800);
    int*   cnt     = (int*)(ws + 405504);
    int*   fill    = (int*)(ws + 606208);
    u16*   xwb     = (u16*)(ws + 806912);
    u16*   entries = (u16*)(ws + 4007936);

    // h1 (bf16, internal) lives in d_out's head; h2 goes to its final slot.
    u16*   h1    = (u16*)d_out;
    u16*   h2_16 = (u16*)d_out + (size_t)NN * CC;
    float* h2_32 = (float*)d_out + (size_t)NN * CC;

    k_probe<<<1, 256, 0, stream>>>((const u32*)x, flag);
    k_zero<<<(NN + 255) / 256, 256, 0, stream>>>(cnt, NN);
    k_deg<<<(EE + 255) / 256, 256, 0, stream>>>(dstv, cnt);
    k_dis<<<(NN + 255) / 256, 256, 0, stream>>>(cnt, dis);

    // CSR build (once, reused by both layers)
    k_scan<<<1, 1024, 0, stream>>>(cnt, rowptr);
    k_fill<<<(NN + 255) / 256, 256, 0, stream>>>(rowptr, fill);
    k_bucket<<<(EE + 255) / 256, 256, 0, stream>>>(srcv, dstv, fill, entries);

    // layer 1: xw1 -> gather (fused norm+agg+bias+tanh) -> h1 (bf16)
    k_xw1<<<(NN + 127) / 128, 256, 0, stream>>>(x, W1, flag, xwb);
    k_gather<<<((NN * 32) + 255) / 256, 256, 0, stream>>>(rowptr, entries, xwb, dis, b1, flag,
                                                          1, h1, (float*)nullptr);

    // layer 2: xw2 (reads h1) -> gather -> h2 (final slot, dtype per flag)
    k_xw2<<<(NN + 127) / 128, 256, 0, stream>>>(h1, W2, flag, xwb);
    k_gather<<<((NN * 32) + 255) / 256, 256, 0, stream>>>(rowptr, entries, xwb, dis, b2, flag,
                                                          0, h2_16, h2_32);

    // classifier
    k_cls<<<(NN * CC + 255) / 256, 256, 0, stream>>>(d_out, Wc, bc, flag);
}